// Round 8
// baseline (543.338 us; speedup 1.0000x reference)
//
#include <hip/hip_runtime.h>

// ---------------------------------------------------------------------------
// GIN 2-layer: out = gin_conv2( relu(gin_conv1(x)) )
// N=100000 nodes, E=1.6M edges, C: 128 -> 256 -> 256 -> 128
// R15 (from R14 @ 543us; baseline R10 @ 532us):
//  - mlp_kernel: 512 THREADS (8 waves), BM=64, same 52KB LDS -> 2 blocks/CU
//    = 16 waves/CU guaranteed; acc halves per thread (~80 VGPR) so HW can
//    reach 3 blocks/CU = 24 waves/CU. R12's A/B showed the MLP is residency-
//    sensitive (more waves > intra-block pipelining): this raises waves/CU
//    33-100% without changing traffic, K-order, or MFMA sequence ->
//    bit-identical output. Wave w owns hidden [w*32,+32) in stage 1 and
//    out-cols [w*NPW2,+NPW2) in stage 2 (NPW2=N2/8).
//  - fill REVERTED to R10-exact bucketed dim3(1024,13) (proven 532 config;
//    R14's sweep was neutral-at-best).
//  - scan2 merged into scan3 (block-offset computed locally per block from
//    bsum[0..98)): one less serial launch.
//  - hist stays fused into cvt (R13/R14). agg_gather scalar addu4 (R10).
// ---------------------------------------------------------------------------

#define N_NODES 100000
#define N_EDGES 1600000
#define NBUCK 13  // fill buckets = dst >> 13 -> 0..12 (512KB write window)

typedef unsigned short ushort_t;
typedef short bf16x8 __attribute__((ext_vector_type(8)));
typedef float floatx4 __attribute__((ext_vector_type(4)));

static __device__ __forceinline__ ushort_t f2bf(float f) {
    unsigned u = __float_as_uint(f);
    u = (u + 0x7FFFu + ((u >> 16) & 1u)) >> 16;
    return (ushort_t)u;
}
static __device__ __forceinline__ unsigned pack2bf(float lo, float hi) {
    return (unsigned)f2bf(lo) | ((unsigned)f2bf(hi) << 16);
}
// accumulate 8 bf16 (as uint4) into 8 f32 (R10-proven form)
static __device__ __forceinline__ void addu4(float* acc, const uint4 v) {
    const unsigned w0 = v.x, w1 = v.y, w2 = v.z, w3 = v.w;
    acc[0] += __uint_as_float(w0 << 16);
    acc[1] += __uint_as_float(w0 & 0xFFFF0000u);
    acc[2] += __uint_as_float(w1 << 16);
    acc[3] += __uint_as_float(w1 & 0xFFFF0000u);
    acc[4] += __uint_as_float(w2 << 16);
    acc[5] += __uint_as_float(w2 & 0xFFFF0000u);
    acc[6] += __uint_as_float(w3 << 16);
    acc[7] += __uint_as_float(w3 & 0xFFFF0000u);
}

#define GLOAD_LDS16(g, l)                                                     \
    __builtin_amdgcn_global_load_lds(                                         \
        (const __attribute__((address_space(1))) void*)(g),                   \
        (__attribute__((address_space(3))) void*)(l), 16, 0, 0)

// ---- fused: x->bf16 (8/thread) + 4 weights->bf16^T + edge histogram ----
#define NX8 (N_NODES * 128 / 8)        // 1,600,000 x-convert threads
#define CVT_TOTAL (NX8 + 196608)       // 1,796,608 = 256 * 7018
#define HIST_THREADS (2048 * 256)      // grid-stride width of hist section
__global__ __launch_bounds__(256) void cvt_fused_kernel(
    const float* __restrict__ X, ushort_t* __restrict__ Xb,
    const float* __restrict__ W1a, const float* __restrict__ W2a,
    const float* __restrict__ W1b, const float* __restrict__ W2b,
    ushort_t* __restrict__ wt1a, ushort_t* __restrict__ wt2a,
    ushort_t* __restrict__ wt1b, ushort_t* __restrict__ wt2b,
    const int* __restrict__ src, const int* __restrict__ dst,
    int* __restrict__ deg, int nE) {
    int i = blockIdx.x * 256 + threadIdx.x;
    if (i < NX8) {
        const float4 a = ((const float4*)X)[2 * i];
        const float4 b = ((const float4*)X)[2 * i + 1];
        uint4 r;
        r.x = pack2bf(a.x, a.y);
        r.y = pack2bf(a.z, a.w);
        r.z = pack2bf(b.x, b.y);
        r.w = pack2bf(b.z, b.w);
        ((uint4*)Xb)[i] = r;
        return;
    }
    if (i < CVT_TOTAL) {
        i -= NX8;
        if (i < 32768) {                       // W1a [128][256]
            int k = i >> 8, n = i & 255;
            wt1a[n * 128 + k] = f2bf(W1a[i]);
        } else if (i < 98304) {                // W2a [256][256]
            int j = i - 32768, k = j >> 8, n = j & 255;
            wt2a[n * 256 + k] = f2bf(W2a[j]);
        } else if (i < 163840) {               // W1b [256][256]
            int j = i - 98304, k = j >> 8, n = j & 255;
            wt1b[n * 256 + k] = f2bf(W1b[j]);
        } else {                               // W2b [256][128]
            int j = i - 163840, k = j >> 7, n = j & 127;
            wt2b[n * 256 + k] = f2bf(W2b[j]);
        }
        return;
    }
    // hist section: deg count (deg memset'd before this kernel)
    for (int e = i - CVT_TOTAL; e < nE; e += HIST_THREADS) {
        int d = dst[e];
        int s = src[e];
        if ((unsigned)d < (unsigned)N_NODES && (unsigned)s < (unsigned)N_NODES)
            atomicAdd(&deg[d], 1);
    }
}

// ---- fill: R10-exact bucketed (residency-order serialized write window) ----
__global__ __launch_bounds__(256) void fill_kernel(const int* __restrict__ src,
                                                   const int* __restrict__ dst,
                                                   int* __restrict__ cursor,
                                                   int* __restrict__ csr_src, int nE) {
    const int bucket = blockIdx.y;
    for (int e = blockIdx.x * 256 + threadIdx.x; e < nE; e += gridDim.x * 256) {
        int d = dst[e];
        int s = src[e];
        if ((unsigned)d < (unsigned)N_NODES && (unsigned)s < (unsigned)N_NODES &&
            (d >> 13) == bucket) {
            int pos = atomicAdd(&cursor[d], 1);
            csr_src[pos] = s;
        }
    }
}

// ---- scan: deg -> row_ptr (exclusive), cursor copy ----
__global__ __launch_bounds__(256) void scan1_kernel(const int* __restrict__ deg,
                                                    int* __restrict__ bsum, int n) {
    __shared__ int l[256];
    int b = blockIdx.x, t = threadIdx.x;
    int base = b * 1024 + t * 4;
    int s = 0;
#pragma unroll
    for (int k = 0; k < 4; ++k) {
        int i = base + k;
        if (i < n) s += deg[i];
    }
    l[t] = s;
    __syncthreads();
    for (int off = 128; off > 0; off >>= 1) {
        if (t < off) l[t] += l[t + off];
        __syncthreads();
    }
    if (t == 0) bsum[b] = l[0];
}

// scan3 with scan2 folded in: block b computes its own offset from bsum[0..b)
__global__ __launch_bounds__(256) void scan3_kernel(const int* __restrict__ deg,
                                                    const int* __restrict__ bsum,
                                                    int* __restrict__ row_ptr,
                                                    int* __restrict__ cursor,
                                                    int n, int nb) {
    __shared__ int l[256];
    __shared__ int boffs;
    int b = blockIdx.x, t = threadIdx.x;
    // block offset = sum of bsum[0..b)
    l[t] = (t < b && t < nb) ? bsum[t] : 0;
    __syncthreads();
    for (int off = 128; off > 0; off >>= 1) {
        if (t < off) l[t] += l[t + off];
        __syncthreads();
    }
    if (t == 0) boffs = l[0];
    __syncthreads();
    // per-block node prefix
    int base = b * 1024 + t * 4;
    int d[4];
    int s = 0;
#pragma unroll
    for (int k = 0; k < 4; ++k) {
        int i = base + k;
        d[k] = (i < n) ? deg[i] : 0;
        s += d[k];
    }
    l[t] = s;
    __syncthreads();
    for (int off = 1; off < 256; off <<= 1) {
        int add = (t >= off) ? l[t - off] : 0;
        __syncthreads();
        l[t] += add;
        __syncthreads();
    }
    int run = boffs + l[t] - s;
#pragma unroll
    for (int k = 0; k < 4; ++k) {
        int i = base + k;
        if (i < n) {
            row_ptr[i] = run;
            cursor[i] = run;
        }
        run += d[k];
    }
}

// ---- per-node gather: T[i] = X[i] + sum_{j in N(i)} X[j]  (bf16 in/out) ----
template <int C, int U>
__global__ __launch_bounds__(256) void agg_gather_kernel(
    const ushort_t* __restrict__ X, ushort_t* __restrict__ T,
    const int* __restrict__ row_ptr, const int* __restrict__ deg,
    const int* __restrict__ csr_src, const ushort_t* __restrict__ zrow, int nN) {
    constexpr int G = C / 8;      // lanes per neighbor row (16 or 32)
    constexpr int NPW = 64 / G;   // neighbors per wave-step (4 or 2)
    constexpr int B = U * NPW;    // neighbors per batch (16)
    const int lane = threadIdx.x & 63;
    const int wid = threadIdx.x >> 6;
    const int node = blockIdx.x * 4 + wid;
    if (node >= nN) return;
    const int sub = lane / G;
    const int coff = (lane % G) * 8;  // ushort offset into row

    float acc[8];
#pragma unroll
    for (int k = 0; k < 8; ++k) acc[k] = 0.f;

    const int base = row_ptr[node];
    const int dg = deg[node];
    for (int j0 = 0; j0 < dg; j0 += 64) {
        int cnt = dg - j0;
        if (cnt > 64) cnt = 64;
        int nidx = (lane < cnt) ? csr_src[base + j0 + lane] : 0;
        if ((unsigned)nidx >= (unsigned)N_NODES) nidx = 0;  // safety clamp
        for (int j = 0; j < cnt; j += B) {
            uint4 v[U];
#pragma unroll
            for (int u = 0; u < U; ++u) {
                int jj = j + u * NPW + sub;
                bool ok = jj < cnt;
                int idx = __shfl(nidx, ok ? jj : 0);
                const ushort_t* p = ok ? (X + (size_t)idx * C) : zrow;
                v[u] = *(const uint4*)(p + coff);
            }
#pragma unroll
            for (int u = 0; u < U; ++u) addu4(acc, v[u]);
        }
    }
    // self term (sub-group 0 only; others would double-count after reduction)
    if (sub == 0) {
        uint4 v = *(const uint4*)(X + (size_t)node * C + coff);
        addu4(acc, v);
    }
    // reduce partials across sub-groups
#pragma unroll
    for (int off = G; off < 64; off <<= 1)
#pragma unroll
        for (int k = 0; k < 8; ++k) acc[k] += __shfl_xor(acc[k], off);

    if (lane < G) {
        uint4 r;
        r.x = pack2bf(acc[0], acc[1]);
        r.y = pack2bf(acc[2], acc[3]);
        r.z = pack2bf(acc[4], acc[5]);
        r.w = pack2bf(acc[6], acc[7]);
        *(uint4*)(T + (size_t)node * C + coff) = r;
    }
}

// ---- fused MLP, 512-thread / 8-wave: C = act2( relu(A@W1+b1) @ W2 + b2 ) ----
// A [M][K1] bf16, Wt1 [256][K1] bf16 (W1^T), Wt2 [N2][256] bf16 (W2^T).
// BM=64 rows/block, 8 waves, 52KB LDS -> >=2 blocks/CU (16 waves/CU); acc
// halves vs 4-wave form (~80 VGPR) so HW may fit 3 blocks/CU (24 waves/CU).
// Stage 1 (role-swapped): wave w owns hidden rows [w*32,+32): av = Wt1 rows,
// bv = A node rows -> acc1[mi<2][ni<4]; u1 packed to U [node][256] with XOR
// swizzle ((node&7)<<4). Stage 2: wave w owns out-cols [w*NPW2,+NPW2),
// NPW2=N2/8; av = U node rows (mi<4), bv = Wt2 rows -> acc2[4][RN2].
// Same BK=32 K-order and MFMA sequence per (node,hid) as R10 -> bit-identical.
template <int K1, int N2, bool RELU2, typename OT>
__global__ __launch_bounds__(512, 4) void mlp_kernel(
    const ushort_t* __restrict__ A, const ushort_t* __restrict__ Wt1,
    const float* __restrict__ b1, const ushort_t* __restrict__ Wt2,
    const float* __restrict__ b2, OT* __restrict__ C, int M) {
    constexpr int N1 = 256, BM = 64, BK = 32;
    constexpr int NPW2 = N2 / 8;    // out-cols per wave in stage 2 (32 or 16)
    constexpr int RN2 = NPW2 / 16;  // frags per wave in stage 2 (2 or 1)
    __shared__ ushort_t As[BM * BK];  // input tile  [64][32]  (4KB)
    __shared__ ushort_t Bs[N1 * BK];  // weight tile [256][32] (16KB, both stages)
    __shared__ ushort_t U[BM * N1];   // u1 tile [64][256], XOR-swizzled (32KB)

    const int lane = threadIdx.x & 63;
    const int wid = threadIdx.x >> 6;   // 0..7
    const int l15 = lane & 15;
    const int q = lane >> 4;
    const int srow = lane >> 2;       // 0..15: row within 16-row DMA group
    const int scol = (lane & 3) * 8;  // ushort offset within 64B row
    const int bm = blockIdx.x * BM;

    floatx4 acc1[2][4];
#pragma unroll
    for (int mi = 0; mi < 2; ++mi)
#pragma unroll
        for (int ni = 0; ni < 4; ++ni) {
            floatx4 z = {0.f, 0.f, 0.f, 0.f};
            acc1[mi][ni] = z;
        }

    // ---- stage 1: u1^T = Wt1 * A^T over K1 ----
    for (int kt = 0; kt < K1; kt += BK) {
        if (wid < 4) {  // As: waves 0..3 stage rows [wid*16,+16)
            const int gr = bm + wid * 16 + srow;
            if (gr < M)
                GLOAD_LDS16(A + (size_t)gr * K1 + kt + scol, &As[(wid * 16) * BK]);
        }
#pragma unroll
        for (int u = 0; u < 2; ++u) {  // Bs: wave w stages rows [w*32,+32)
            const int row = wid * 32 + u * 16;
            GLOAD_LDS16(Wt1 + (size_t)(row + srow) * K1 + kt + scol, &Bs[row * BK]);
        }
        __syncthreads();  // drains vmcnt(0): DMA complete
        bf16x8 av[2], bv[4];
#pragma unroll
        for (int mi = 0; mi < 2; ++mi)
            av[mi] = *(const bf16x8*)&Bs[(wid * 32 + mi * 16 + l15) * BK + q * 8];
#pragma unroll
        for (int ni = 0; ni < 4; ++ni)
            bv[ni] = *(const bf16x8*)&As[(ni * 16 + l15) * BK + q * 8];
#pragma unroll
        for (int mi = 0; mi < 2; ++mi)
#pragma unroll
            for (int ni = 0; ni < 4; ++ni)
                acc1[mi][ni] = __builtin_amdgcn_mfma_f32_16x16x32_bf16(
                    av[mi], bv[ni], acc1[mi][ni], 0, 0, 0);
        __syncthreads();
    }

    // ---- bias1 + relu + pack -> U[node][hidden] (swizzled) ----
#pragma unroll
    for (int mi = 0; mi < 2; ++mi) {
        const int h0 = wid * 32 + mi * 16 + q * 4;
        const float4 b4 = *(const float4*)&b1[h0];
#pragma unroll
        for (int ni = 0; ni < 4; ++ni) {
            const int node = ni * 16 + l15;
            float v0 = acc1[mi][ni][0] + b4.x; v0 = v0 > 0.f ? v0 : 0.f;
            float v1 = acc1[mi][ni][1] + b4.y; v1 = v1 > 0.f ? v1 : 0.f;
            float v2 = acc1[mi][ni][2] + b4.z; v2 = v2 > 0.f ? v2 : 0.f;
            float v3 = acc1[mi][ni][3] + b4.w; v3 = v3 > 0.f ? v3 : 0.f;
            uint2 w;
            w.x = pack2bf(v0, v1);
            w.y = pack2bf(v2, v3);
            int byte = node * (N1 * 2) + h0 * 2;
            byte ^= (node & 7) << 4;
            *(uint2*)((char*)U + byte) = w;
        }
    }
    __syncthreads();

    // ---- stage 2: C = u1 @ W2 over N1 ----
    floatx4 acc2[4][RN2];
#pragma unroll
    for (int mi = 0; mi < 4; ++mi)
#pragma unroll
        for (int ni = 0; ni < RN2; ++ni) {
            floatx4 z = {0.f, 0.f, 0.f, 0.f};
            acc2[mi][ni] = z;
        }

    for (int kt = 0; kt < N1; kt += BK) {
#pragma unroll
        for (int u = 0; u < 2; ++u) {  // Bs <- Wt2 rows [w*32,+32), guarded
            const int row = wid * 32 + u * 16;
            if (row < N2)
                GLOAD_LDS16(Wt2 + (size_t)(row + srow) * N1 + kt + scol,
                            &Bs[row * BK]);
        }
        __syncthreads();
        bf16x8 av[4], bv[RN2];
#pragma unroll
        for (int mi = 0; mi < 4; ++mi) {
            const int node = mi * 16 + l15;
            const int byte =
                (node * (N1 * 2) + kt * 2 + q * 16) ^ ((node & 7) << 4);
            av[mi] = *(const bf16x8*)((const char*)U + byte);
        }
#pragma unroll
        for (int ni = 0; ni < RN2; ++ni)
            bv[ni] = *(const bf16x8*)&Bs[(wid * NPW2 + ni * 16 + l15) * BK + q * 8];
#pragma unroll
        for (int mi = 0; mi < 4; ++mi)
#pragma unroll
            for (int ni = 0; ni < RN2; ++ni)
                acc2[mi][ni] = __builtin_amdgcn_mfma_f32_16x16x32_bf16(
                    av[mi], bv[ni], acc2[mi][ni], 0, 0, 0);
        __syncthreads();
    }

    // ---- epilogue: bias2 (+relu), store ----
    float bval[RN2];
#pragma unroll
    for (int ni = 0; ni < RN2; ++ni) bval[ni] = b2[wid * NPW2 + ni * 16 + l15];
#pragma unroll
    for (int mi = 0; mi < 4; ++mi) {
#pragma unroll
        for (int r = 0; r < 4; ++r) {
            const int row = bm + mi * 16 + q * 4 + r;
            if (row < M) {
#pragma unroll
                for (int ni = 0; ni < RN2; ++ni) {
                    const int col = wid * NPW2 + ni * 16 + l15;
                    float v = acc2[mi][ni][r] + bval[ni];
                    if (RELU2) v = v > 0.f ? v : 0.f;
                    if constexpr (sizeof(OT) == 2)
                        C[(size_t)row * N2 + col] = f2bf(v);
                    else
                        C[(size_t)row * N2 + col] = v;
                }
            }
        }
    }
}

extern "C" void kernel_launch(void* const* d_in, const int* in_sizes, int n_in,
                              void* d_out, int out_size, void* d_ws, size_t ws_size,
                              hipStream_t stream) {
    const float* x   = (const float*)d_in[0];
    const int*   ei  = (const int*)d_in[1];
    const float* W1a = (const float*)d_in[2];
    const float* b1a = (const float*)d_in[3];
    const float* W2a = (const float*)d_in[4];
    const float* b2a = (const float*)d_in[5];
    const float* W1b = (const float*)d_in[6];
    const float* b1b = (const float*)d_in[7];
    const float* W2b = (const float*)d_in[8];
    const float* b2b = (const float*)d_in[9];
    const int* src = ei;
    const int* dst = ei + N_EDGES;
    float* out = (float*)d_out;

    // ---- workspace layout (~85MB; 103MB proven to fit) ----
    char* base = (char*)d_ws;
    size_t o = 0;
    ushort_t* wt1a = (ushort_t*)(base + o); o += 128 * 256 * 2;
    ushort_t* wt2a = (ushort_t*)(base + o); o += 256 * 256 * 2;
    ushort_t* wt1b = (ushort_t*)(base + o); o += 256 * 256 * 2;
    ushort_t* wt2b = (ushort_t*)(base + o); o += 256 * 128 * 2;
    o = (o + 255) & ~(size_t)255;
    ushort_t* zrow = (ushort_t*)(base + o); o += 512;          // memset'd
    int* deg     = (int*)(base + o); o += (size_t)N_NODES * 4; // memset'd
    int* row_ptr = (int*)(base + o); o += (size_t)N_NODES * 4;
    int* cursor  = (int*)(base + o); o += (size_t)N_NODES * 4;
    int* bsum    = (int*)(base + o); o += 128 * 4;
    o = (o + 255) & ~(size_t)255;
    int* csr_src = (int*)(base + o); o += (size_t)N_EDGES * 4;
    o = (o + 255) & ~(size_t)255;
    ushort_t* t1   = (ushort_t*)(base + o); o += (size_t)N_NODES * 128 * 2;
    ushort_t* tbig = (ushort_t*)(base + o); o += (size_t)N_NODES * 256 * 2;  // t2
    o += 128 * 1024;  // guard
    (void)ws_size; (void)o; (void)in_sizes; (void)n_in; (void)out_size;

    ushort_t* inter = (ushort_t*)d_out;  // xb, then h (d_out = 51.2MB)
    ushort_t* xb    = (ushort_t*)d_out;  // bf16 x, dead after agg1 (mlp_a overwrites)

    // ---- memset FIRST (deg must be zero before fused hist) ----
    hipMemsetAsync(zrow, 0, 512 + (size_t)N_NODES * 4, stream);  // zrow + deg

    // ---- conversions + hist in one launch ----
    cvt_fused_kernel<<<CVT_TOTAL / 256 + 2048, 256, 0, stream>>>(
        x, xb, W1a, W2a, W1b, W2b, wt1a, wt2a, wt1b, wt2b, src, dst, deg, N_EDGES);

    // ---- CSR: scan1 -> merged scan3 -> bucketed fill (R10) ----
    const int NB = (N_NODES + 1023) / 1024;  // 98
    scan1_kernel<<<NB, 256, 0, stream>>>(deg, bsum, N_NODES);
    scan3_kernel<<<NB, 256, 0, stream>>>(deg, bsum, row_ptr, cursor, N_NODES, NB);
    fill_kernel<<<dim3(1024, NBUCK), 256, 0, stream>>>(src, dst, cursor, csr_src,
                                                       N_EDGES);

    const int ga = (N_NODES + 3) / 4;        // 25000
    const int gf = (N_NODES + 63) / 64;      // 1563 fused-MLP blocks

    // ---- layer 1 ----
    // t1 = xb + segsum(xb)        (d_out -> ws)
    agg_gather_kernel<128, 4><<<ga, 256, 0, stream>>>(xb, t1, row_ptr, deg,
                                                      csr_src, zrow, N_NODES);
    // h = relu( relu(t1@W1a+b1a) @ W2a + b2a )   (ws -> d_out, overwrites dead xb)
    mlp_kernel<128, 256, true, ushort_t><<<gf, 512, 0, stream>>>(
        t1, wt1a, b1a, wt2a, b2a, inter, N_NODES);

    // ---- layer 2 ----
    // t2 = h + segsum(h)          (d_out -> ws)
    agg_gather_kernel<256, 8><<<ga, 256, 0, stream>>>(inter, tbig, row_ptr,
                                                      deg, csr_src, zrow, N_NODES);
    // out = relu(t2@W1b+b1b) @ W2b + b2b         (ws -> d_out, overwrites dead h)
    mlp_kernel<256, 128, false, float><<<gf, 512, 0, stream>>>(
        tbig, wt1b, b1b, wt2b, b2b, out, N_NODES);
}

// Round 9
// 538.179 us; speedup vs baseline: 1.0096x; 1.0096x over previous
//
#include <hip/hip_runtime.h>

// ---------------------------------------------------------------------------
// GIN 2-layer: out = gin_conv2( relu(gin_conv1(x)) )
// N=100000 nodes, E=1.6M edges, C: 128 -> 256 -> 256 -> 128
// R16 (from R15 @ 543us; best R10 @ 532us):
//  - mlp_kernel REVERTED to R10-exact 4-wave form. R12 (dbuf@2blk/CU) and
//    R15 (8-wave) both neutral-negative -> MLPs are NOT the hidden budget;
//    stop touching them.
//  - agg_gather: MLP(memory-level-parallelism) experiment - U doubled
//    (C=128: 4->8, C=256: 8->16 in-flight 16B loads/lane, VGPR ~40->~80,
//    cap still >=24 waves/CU > observed 18) + packed (row_ptr,deg) int2
//    (one dependent header load instead of two). Neighbor accumulation
//    order unchanged -> bit-identical. agg256 is directly measurable in
//    top-5: if unchanged, ~3.9TB/s L2-miss rate is the random-gather
//    fabric ceiling and agg is rooflined.
//  - CSR: R10-exact bucketed fill (1024,13); scan2 merged into scan3 (R15,
//    keeps launch count down); scan3 additionally writes packed rpd[].
//  - cvt+hist fused (R13). Layout/order of all math unchanged.
// ---------------------------------------------------------------------------

#define N_NODES 100000
#define N_EDGES 1600000
#define NBUCK 13  // fill buckets = dst >> 13 -> 0..12 (512KB write window)

typedef unsigned short ushort_t;
typedef short bf16x8 __attribute__((ext_vector_type(8)));
typedef float floatx4 __attribute__((ext_vector_type(4)));

static __device__ __forceinline__ ushort_t f2bf(float f) {
    unsigned u = __float_as_uint(f);
    u = (u + 0x7FFFu + ((u >> 16) & 1u)) >> 16;
    return (ushort_t)u;
}
static __device__ __forceinline__ unsigned pack2bf(float lo, float hi) {
    return (unsigned)f2bf(lo) | ((unsigned)f2bf(hi) << 16);
}
// accumulate 8 bf16 (as uint4) into 8 f32 (R10-proven form)
static __device__ __forceinline__ void addu4(float* acc, const uint4 v) {
    const unsigned w0 = v.x, w1 = v.y, w2 = v.z, w3 = v.w;
    acc[0] += __uint_as_float(w0 << 16);
    acc[1] += __uint_as_float(w0 & 0xFFFF0000u);
    acc[2] += __uint_as_float(w1 << 16);
    acc[3] += __uint_as_float(w1 & 0xFFFF0000u);
    acc[4] += __uint_as_float(w2 << 16);
    acc[5] += __uint_as_float(w2 & 0xFFFF0000u);
    acc[6] += __uint_as_float(w3 << 16);
    acc[7] += __uint_as_float(w3 & 0xFFFF0000u);
}

#define GLOAD_LDS16(g, l)                                                     \
    __builtin_amdgcn_global_load_lds(                                         \
        (const __attribute__((address_space(1))) void*)(g),                   \
        (__attribute__((address_space(3))) void*)(l), 16, 0, 0)

// ---- fused: x->bf16 (8/thread) + 4 weights->bf16^T + edge histogram ----
#define NX8 (N_NODES * 128 / 8)        // 1,600,000 x-convert threads
#define CVT_TOTAL (NX8 + 196608)       // 1,796,608 = 256 * 7018
#define HIST_THREADS (2048 * 256)      // grid-stride width of hist section
__global__ __launch_bounds__(256) void cvt_fused_kernel(
    const float* __restrict__ X, ushort_t* __restrict__ Xb,
    const float* __restrict__ W1a, const float* __restrict__ W2a,
    const float* __restrict__ W1b, const float* __restrict__ W2b,
    ushort_t* __restrict__ wt1a, ushort_t* __restrict__ wt2a,
    ushort_t* __restrict__ wt1b, ushort_t* __restrict__ wt2b,
    const int* __restrict__ src, const int* __restrict__ dst,
    int* __restrict__ deg, int nE) {
    int i = blockIdx.x * 256 + threadIdx.x;
    if (i < NX8) {
        const float4 a = ((const float4*)X)[2 * i];
        const float4 b = ((const float4*)X)[2 * i + 1];
        uint4 r;
        r.x = pack2bf(a.x, a.y);
        r.y = pack2bf(a.z, a.w);
        r.z = pack2bf(b.x, b.y);
        r.w = pack2bf(b.z, b.w);
        ((uint4*)Xb)[i] = r;
        return;
    }
    if (i < CVT_TOTAL) {
        i -= NX8;
        if (i < 32768) {                       // W1a [128][256]
            int k = i >> 8, n = i & 255;
            wt1a[n * 128 + k] = f2bf(W1a[i]);
        } else if (i < 98304) {                // W2a [256][256]
            int j = i - 32768, k = j >> 8, n = j & 255;
            wt2a[n * 256 + k] = f2bf(W2a[j]);
        } else if (i < 163840) {               // W1b [256][256]
            int j = i - 98304, k = j >> 8, n = j & 255;
            wt1b[n * 256 + k] = f2bf(W1b[j]);
        } else {                               // W2b [256][128]
            int j = i - 163840, k = j >> 7, n = j & 127;
            wt2b[n * 256 + k] = f2bf(W2b[j]);
        }
        return;
    }
    // hist section: deg count (deg memset'd before this kernel)
    for (int e = i - CVT_TOTAL; e < nE; e += HIST_THREADS) {
        int d = dst[e];
        int s = src[e];
        if ((unsigned)d < (unsigned)N_NODES && (unsigned)s < (unsigned)N_NODES)
            atomicAdd(&deg[d], 1);
    }
}

// ---- fill: R10-exact bucketed (residency-order serialized write window) ----
__global__ __launch_bounds__(256) void fill_kernel(const int* __restrict__ src,
                                                   const int* __restrict__ dst,
                                                   int* __restrict__ cursor,
                                                   int* __restrict__ csr_src, int nE) {
    const int bucket = blockIdx.y;
    for (int e = blockIdx.x * 256 + threadIdx.x; e < nE; e += gridDim.x * 256) {
        int d = dst[e];
        int s = src[e];
        if ((unsigned)d < (unsigned)N_NODES && (unsigned)s < (unsigned)N_NODES &&
            (d >> 13) == bucket) {
            int pos = atomicAdd(&cursor[d], 1);
            csr_src[pos] = s;
        }
    }
}

// ---- scan: deg -> row_ptr (exclusive), cursor copy, packed rpd ----
__global__ __launch_bounds__(256) void scan1_kernel(const int* __restrict__ deg,
                                                    int* __restrict__ bsum, int n) {
    __shared__ int l[256];
    int b = blockIdx.x, t = threadIdx.x;
    int base = b * 1024 + t * 4;
    int s = 0;
#pragma unroll
    for (int k = 0; k < 4; ++k) {
        int i = base + k;
        if (i < n) s += deg[i];
    }
    l[t] = s;
    __syncthreads();
    for (int off = 128; off > 0; off >>= 1) {
        if (t < off) l[t] += l[t + off];
        __syncthreads();
    }
    if (t == 0) bsum[b] = l[0];
}

// scan3 with scan2 folded in: block b computes its own offset from bsum[0..b)
__global__ __launch_bounds__(256) void scan3_kernel(const int* __restrict__ deg,
                                                    const int* __restrict__ bsum,
                                                    int* __restrict__ row_ptr,
                                                    int* __restrict__ cursor,
                                                    int2* __restrict__ rpd,
                                                    int n, int nb) {
    __shared__ int l[256];
    __shared__ int boffs;
    int b = blockIdx.x, t = threadIdx.x;
    // block offset = sum of bsum[0..b)
    l[t] = (t < b && t < nb) ? bsum[t] : 0;
    __syncthreads();
    for (int off = 128; off > 0; off >>= 1) {
        if (t < off) l[t] += l[t + off];
        __syncthreads();
    }
    if (t == 0) boffs = l[0];
    __syncthreads();
    // per-block node prefix
    int base = b * 1024 + t * 4;
    int d[4];
    int s = 0;
#pragma unroll
    for (int k = 0; k < 4; ++k) {
        int i = base + k;
        d[k] = (i < n) ? deg[i] : 0;
        s += d[k];
    }
    l[t] = s;
    __syncthreads();
    for (int off = 1; off < 256; off <<= 1) {
        int add = (t >= off) ? l[t - off] : 0;
        __syncthreads();
        l[t] += add;
        __syncthreads();
    }
    int run = boffs + l[t] - s;
#pragma unroll
    for (int k = 0; k < 4; ++k) {
        int i = base + k;
        if (i < n) {
            row_ptr[i] = run;
            cursor[i] = run;
            rpd[i] = make_int2(run, d[k]);
        }
        run += d[k];
    }
}

// ---- per-node gather: T[i] = X[i] + sum_{j in N(i)} X[j]  (bf16 in/out) ----
// Lane loads 16B. G=C/8 lanes per neighbor row, NPW=64/G neighbors per step.
// Fully-predicated batches of U*NPW neighbors: invalid slots load zrow.
// U doubled vs R10 (more loads in flight); (row_ptr,deg) packed in one int2.
template <int C, int U>
__global__ __launch_bounds__(256) void agg_gather_kernel(
    const ushort_t* __restrict__ X, ushort_t* __restrict__ T,
    const int2* __restrict__ rpd, const int* __restrict__ csr_src,
    const ushort_t* __restrict__ zrow, int nN) {
    constexpr int G = C / 8;      // lanes per neighbor row (16 or 32)
    constexpr int NPW = 64 / G;   // neighbors per wave-step (4 or 2)
    constexpr int B = U * NPW;    // neighbors per batch (32)
    const int lane = threadIdx.x & 63;
    const int wid = threadIdx.x >> 6;
    const int node = blockIdx.x * 4 + wid;
    if (node >= nN) return;
    const int sub = lane / G;
    const int coff = (lane % G) * 8;  // ushort offset into row

    float acc[8];
#pragma unroll
    for (int k = 0; k < 8; ++k) acc[k] = 0.f;

    const int2 rd = rpd[node];
    const int base = rd.x;
    const int dg = rd.y;
    for (int j0 = 0; j0 < dg; j0 += 64) {
        int cnt = dg - j0;
        if (cnt > 64) cnt = 64;
        int nidx = (lane < cnt) ? csr_src[base + j0 + lane] : 0;
        if ((unsigned)nidx >= (unsigned)N_NODES) nidx = 0;  // safety clamp
        for (int j = 0; j < cnt; j += B) {
            uint4 v[U];
#pragma unroll
            for (int u = 0; u < U; ++u) {
                int jj = j + u * NPW + sub;
                bool ok = jj < cnt;
                int idx = __shfl(nidx, ok ? jj : 0);
                const ushort_t* p = ok ? (X + (size_t)idx * C) : zrow;
                v[u] = *(const uint4*)(p + coff);
            }
#pragma unroll
            for (int u = 0; u < U; ++u) addu4(acc, v[u]);
        }
    }
    // self term (sub-group 0 only; others would double-count after reduction)
    if (sub == 0) {
        uint4 v = *(const uint4*)(X + (size_t)node * C + coff);
        addu4(acc, v);
    }
    // reduce partials across sub-groups
#pragma unroll
    for (int off = G; off < 64; off <<= 1)
#pragma unroll
        for (int k = 0; k < 8; ++k) acc[k] += __shfl_xor(acc[k], off);

    if (lane < G) {
        uint4 r;
        r.x = pack2bf(acc[0], acc[1]);
        r.y = pack2bf(acc[2], acc[3]);
        r.z = pack2bf(acc[4], acc[5]);
        r.w = pack2bf(acc[6], acc[7]);
        *(uint4*)(T + (size_t)node * C + coff) = r;
    }
}

// ---- fused MLP (R10-exact): C = act2( relu(A@W1+b1) @ W2 + b2 ) ----
// A [M][K1] bf16, Wt1 [256][K1] bf16 (W1 transposed), Wt2 [N2][256] bf16.
// BM=64 rows/block, 256 threads (4 waves), 3 blocks/CU (52KB LDS).
// Stage 1 role-swapped (av = Wt1 rows, bv = A rows) -> lane holds 4
// hidden-contiguous f32 -> packed uint2 LDS write of u1 [node][256],
// XOR-swizzle ((node&7)<<4). Stage 2: av = U node rows, bv = Wt2 rows.
template <int K1, int N2, bool RELU2, typename OT>
__global__ __launch_bounds__(256, 3) void mlp_kernel(
    const ushort_t* __restrict__ A, const ushort_t* __restrict__ Wt1,
    const float* __restrict__ b1, const ushort_t* __restrict__ Wt2,
    const float* __restrict__ b2, OT* __restrict__ C, int M) {
    constexpr int N1 = 256, BM = 64, BK = 32;
    constexpr int NPW2 = N2 / 4;    // out-cols per wave in stage 2 (64 or 32)
    constexpr int RN2 = NPW2 / 16;  // frags / staging issues per wave (4 or 2)
    __shared__ ushort_t As[BM * BK];  // input tile  [64][32]
    __shared__ ushort_t Bs[N1 * BK];  // weight tile [256][32] (both stages)
    __shared__ ushort_t U[BM * N1];   // u1 tile [64][256], XOR-swizzled

    const int lane = threadIdx.x & 63;
    const int wid = threadIdx.x >> 6;
    const int l15 = lane & 15;
    const int q = lane >> 4;
    const int srow = lane >> 2;       // 0..15: row within 16-row DMA group
    const int scol = (lane & 3) * 8;  // ushort offset within 64B row
    const int bm = blockIdx.x * BM;

    floatx4 acc[4][4];
#pragma unroll
    for (int mi = 0; mi < 4; ++mi)
#pragma unroll
        for (int ni = 0; ni < 4; ++ni) {
            floatx4 z = {0.f, 0.f, 0.f, 0.f};
            acc[mi][ni] = z;
        }

    // ---- stage 1: u1^T = Wt1 * A^T over K1 ----
    for (int kt = 0; kt < K1; kt += BK) {
        {   // As: wave wid stages rows [wid*16, wid*16+16)
            const int gr = bm + wid * 16 + srow;
            if (gr < M)
                GLOAD_LDS16(A + (size_t)gr * K1 + kt + scol, &As[(wid * 16) * BK]);
        }
#pragma unroll
        for (int u = 0; u < 4; ++u) {  // Bs: wave wid stages rows [wid*64, +64)
            const int row = wid * 64 + u * 16;
            GLOAD_LDS16(Wt1 + (size_t)(row + srow) * K1 + kt + scol, &Bs[row * BK]);
        }
        __syncthreads();  // drains vmcnt(0): DMA complete
        bf16x8 av[4], bv[4];
#pragma unroll
        for (int mi = 0; mi < 4; ++mi)
            av[mi] = *(const bf16x8*)&Bs[(wid * 64 + mi * 16 + l15) * BK + q * 8];
#pragma unroll
        for (int ni = 0; ni < 4; ++ni)
            bv[ni] = *(const bf16x8*)&As[(ni * 16 + l15) * BK + q * 8];
#pragma unroll
        for (int mi = 0; mi < 4; ++mi)
#pragma unroll
            for (int ni = 0; ni < 4; ++ni)
                acc[mi][ni] = __builtin_amdgcn_mfma_f32_16x16x32_bf16(
                    av[mi], bv[ni], acc[mi][ni], 0, 0, 0);
        __syncthreads();
    }

    // ---- bias1 + relu + pack -> U[node][hidden] (swizzled) ----
#pragma unroll
    for (int mi = 0; mi < 4; ++mi) {
        const int h0 = wid * 64 + mi * 16 + q * 4;
        const float4 b4 = *(const float4*)&b1[h0];
#pragma unroll
        for (int ni = 0; ni < 4; ++ni) {
            const int node = ni * 16 + l15;
            float v0 = acc[mi][ni][0] + b4.x; v0 = v0 > 0.f ? v0 : 0.f;
            float v1 = acc[mi][ni][1] + b4.y; v1 = v1 > 0.f ? v1 : 0.f;
            float v2 = acc[mi][ni][2] + b4.z; v2 = v2 > 0.f ? v2 : 0.f;
            float v3 = acc[mi][ni][3] + b4.w; v3 = v3 > 0.f ? v3 : 0.f;
            uint2 w;
            w.x = pack2bf(v0, v1);
            w.y = pack2bf(v2, v3);
            int byte = node * (N1 * 2) + h0 * 2;
            byte ^= (node & 7) << 4;
            *(uint2*)((char*)U + byte) = w;
        }
    }
    __syncthreads();

    // ---- stage 2: C = u1 @ W2 over N1 ----
#pragma unroll
    for (int mi = 0; mi < 4; ++mi)
#pragma unroll
        for (int ni = 0; ni < 4; ++ni) {
            floatx4 z = {0.f, 0.f, 0.f, 0.f};
            acc[mi][ni] = z;
        }

    for (int kt = 0; kt < N1; kt += BK) {
#pragma unroll
        for (int u = 0; u < RN2; ++u) {  // Bs <- Wt2 rows [wid*NPW2, +NPW2)
            const int row = wid * NPW2 + u * 16;
            GLOAD_LDS16(Wt2 + (size_t)(row + srow) * N1 + kt + scol, &Bs[row * BK]);
        }
        __syncthreads();
        bf16x8 av[4], bv[RN2];
#pragma unroll
        for (int mi = 0; mi < 4; ++mi) {
            const int node = mi * 16 + l15;
            const int byte =
                (node * (N1 * 2) + kt * 2 + q * 16) ^ ((node & 7) << 4);
            av[mi] = *(const bf16x8*)((const char*)U + byte);
        }
#pragma unroll
        for (int ni = 0; ni < RN2; ++ni)
            bv[ni] = *(const bf16x8*)&Bs[(wid * NPW2 + ni * 16 + l15) * BK + q * 8];
#pragma unroll
        for (int mi = 0; mi < 4; ++mi)
#pragma unroll
            for (int ni = 0; ni < RN2; ++ni)
                acc[mi][ni] = __builtin_amdgcn_mfma_f32_16x16x32_bf16(
                    av[mi], bv[ni], acc[mi][ni], 0, 0, 0);
        __syncthreads();
    }

    // ---- epilogue: bias2 (+relu), store ----
    float bval[RN2];
#pragma unroll
    for (int ni = 0; ni < RN2; ++ni) bval[ni] = b2[wid * NPW2 + ni * 16 + l15];
#pragma unroll
    for (int mi = 0; mi < 4; ++mi) {
#pragma unroll
        for (int r = 0; r < 4; ++r) {
            const int row = bm + mi * 16 + q * 4 + r;
            if (row < M) {
#pragma unroll
                for (int ni = 0; ni < RN2; ++ni) {
                    const int col = wid * NPW2 + ni * 16 + l15;
                    float v = acc[mi][ni][r] + bval[ni];
                    if (RELU2) v = v > 0.f ? v : 0.f;
                    if constexpr (sizeof(OT) == 2)
                        C[(size_t)row * N2 + col] = f2bf(v);
                    else
                        C[(size_t)row * N2 + col] = v;
                }
            }
        }
    }
}

extern "C" void kernel_launch(void* const* d_in, const int* in_sizes, int n_in,
                              void* d_out, int out_size, void* d_ws, size_t ws_size,
                              hipStream_t stream) {
    const float* x   = (const float*)d_in[0];
    const int*   ei  = (const int*)d_in[1];
    const float* W1a = (const float*)d_in[2];
    const float* b1a = (const float*)d_in[3];
    const float* W2a = (const float*)d_in[4];
    const float* b2a = (const float*)d_in[5];
    const float* W1b = (const float*)d_in[6];
    const float* b1b = (const float*)d_in[7];
    const float* W2b = (const float*)d_in[8];
    const float* b2b = (const float*)d_in[9];
    const int* src = ei;
    const int* dst = ei + N_EDGES;
    float* out = (float*)d_out;

    // ---- workspace layout (~86MB; 103MB proven to fit) ----
    char* base = (char*)d_ws;
    size_t o = 0;
    ushort_t* wt1a = (ushort_t*)(base + o); o += 128 * 256 * 2;
    ushort_t* wt2a = (ushort_t*)(base + o); o += 256 * 256 * 2;
    ushort_t* wt1b = (ushort_t*)(base + o); o += 256 * 256 * 2;
    ushort_t* wt2b = (ushort_t*)(base + o); o += 256 * 128 * 2;
    o = (o + 255) & ~(size_t)255;
    ushort_t* zrow = (ushort_t*)(base + o); o += 512;          // memset'd
    int* deg     = (int*)(base + o); o += (size_t)N_NODES * 4; // memset'd
    int* row_ptr = (int*)(base + o); o += (size_t)N_NODES * 4;
    int* cursor  = (int*)(base + o); o += (size_t)N_NODES * 4;
    int* bsum    = (int*)(base + o); o += 128 * 4;
    o = (o + 255) & ~(size_t)255;
    int2* rpd    = (int2*)(base + o); o += (size_t)N_NODES * 8;
    o = (o + 255) & ~(size_t)255;
    int* csr_src = (int*)(base + o); o += (size_t)N_EDGES * 4;
    o = (o + 255) & ~(size_t)255;
    ushort_t* t1   = (ushort_t*)(base + o); o += (size_t)N_NODES * 128 * 2;
    ushort_t* tbig = (ushort_t*)(base + o); o += (size_t)N_NODES * 256 * 2;  // t2
    o += 128 * 1024;  // guard
    (void)ws_size; (void)o; (void)in_sizes; (void)n_in; (void)out_size;

    ushort_t* inter = (ushort_t*)d_out;  // xb, then h (d_out = 51.2MB)
    ushort_t* xb    = (ushort_t*)d_out;  // bf16 x, dead after agg1 (mlp_a overwrites)

    // ---- memset FIRST (deg must be zero before fused hist) ----
    hipMemsetAsync(zrow, 0, 512 + (size_t)N_NODES * 4, stream);  // zrow + deg

    // ---- conversions + hist in one launch ----
    cvt_fused_kernel<<<CVT_TOTAL / 256 + 2048, 256, 0, stream>>>(
        x, xb, W1a, W2a, W1b, W2b, wt1a, wt2a, wt1b, wt2b, src, dst, deg, N_EDGES);

    // ---- CSR: scan1 -> merged scan3 (writes rpd) -> bucketed fill (R10) ----
    const int NB = (N_NODES + 1023) / 1024;  // 98
    scan1_kernel<<<NB, 256, 0, stream>>>(deg, bsum, N_NODES);
    scan3_kernel<<<NB, 256, 0, stream>>>(deg, bsum, row_ptr, cursor, rpd,
                                         N_NODES, NB);
    fill_kernel<<<dim3(1024, NBUCK), 256, 0, stream>>>(src, dst, cursor, csr_src,
                                                       N_EDGES);

    const int ga = (N_NODES + 3) / 4;        // 25000
    const int gf = (N_NODES + 63) / 64;      // 1563 fused-MLP blocks

    // ---- layer 1 ----
    // t1 = xb + segsum(xb)        (d_out -> ws)
    agg_gather_kernel<128, 8><<<ga, 256, 0, stream>>>(xb, t1, rpd, csr_src,
                                                      zrow, N_NODES);
    // h = relu( relu(t1@W1a+b1a) @ W2a + b2a )   (ws -> d_out, overwrites dead xb)
    mlp_kernel<128, 256, true, ushort_t><<<gf, 256, 0, stream>>>(
        t1, wt1a, b1a, wt2a, b2a, inter, N_NODES);

    // ---- layer 2 ----
    // t2 = h + segsum(h)          (d_out -> ws)
    agg_gather_kernel<256, 16><<<ga, 256, 0, stream>>>(inter, tbig, rpd,
                                                       csr_src, zrow, N_NODES);
    // out = relu(t2@W1b+b1b) @ W2b + b2b         (ws -> d_out, overwrites dead h)
    mlp_kernel<256, 128, false, float><<<gf, 256, 0, stream>>>(
        tbig, wt1b, b1b, wt2b, b2b, out, N_NODES);
}

// Round 10
// 527.535 us; speedup vs baseline: 1.0300x; 1.0202x over previous
//
#include <hip/hip_runtime.h>

// ---------------------------------------------------------------------------
// GIN 2-layer: out = gin_conv2( relu(gin_conv1(x)) )
// N=100000 nodes, E=1.6M edges, C: 128 -> 256 -> 256 -> 128
// R17 — RESTORE-BEST (R10 @ 532us config + proven-harmless launch trims):
//  - agg_gather: R10-exact (U=4/8, separate row_ptr/deg, VGPR 40). R16's
//    U-doubling regressed (118->123us, Occ 57->42%): gather is at the
//    per-CU service-rate ceiling (819MB/118us = 11.3 B/cyc/CU ~= m13
//    streaming ceiling), not depth-starved. Bytes irreducible (random graph).
//  - mlp_kernel: R10-exact 4-wave (R12 dbuf and R15 8-wave both neutral-neg).
//  - fill: R10-exact bucketed dim3(1024,13) (R11/R13/R14 alternatives all
//    neutral or worse; bucketing's write-window locality via residency-order
//    serialization is the proven form).
//  - kept: cvt+hist single dispatch (R13), scan2 folded into scan3 (R15).
// Component ledger (measured/derived): agg256 118 + agg128 ~62 + mlp ~50x2 +
// fill ~84 + cvt/hist ~25 + scans ~8 -> each at measured roofline or proven
// insensitive across 3 structural variants.
// ---------------------------------------------------------------------------

#define N_NODES 100000
#define N_EDGES 1600000
#define NBUCK 13  // fill buckets = dst >> 13 -> 0..12 (512KB write window)

typedef unsigned short ushort_t;
typedef short bf16x8 __attribute__((ext_vector_type(8)));
typedef float floatx4 __attribute__((ext_vector_type(4)));

static __device__ __forceinline__ ushort_t f2bf(float f) {
    unsigned u = __float_as_uint(f);
    u = (u + 0x7FFFu + ((u >> 16) & 1u)) >> 16;
    return (ushort_t)u;
}
static __device__ __forceinline__ unsigned pack2bf(float lo, float hi) {
    return (unsigned)f2bf(lo) | ((unsigned)f2bf(hi) << 16);
}
// accumulate 8 bf16 (as uint4) into 8 f32 (R10-proven form)
static __device__ __forceinline__ void addu4(float* acc, const uint4 v) {
    const unsigned w0 = v.x, w1 = v.y, w2 = v.z, w3 = v.w;
    acc[0] += __uint_as_float(w0 << 16);
    acc[1] += __uint_as_float(w0 & 0xFFFF0000u);
    acc[2] += __uint_as_float(w1 << 16);
    acc[3] += __uint_as_float(w1 & 0xFFFF0000u);
    acc[4] += __uint_as_float(w2 << 16);
    acc[5] += __uint_as_float(w2 & 0xFFFF0000u);
    acc[6] += __uint_as_float(w3 << 16);
    acc[7] += __uint_as_float(w3 & 0xFFFF0000u);
}

#define GLOAD_LDS16(g, l)                                                     \
    __builtin_amdgcn_global_load_lds(                                         \
        (const __attribute__((address_space(1))) void*)(g),                   \
        (__attribute__((address_space(3))) void*)(l), 16, 0, 0)

// ---- fused: x->bf16 (8/thread) + 4 weights->bf16^T + edge histogram ----
#define NX8 (N_NODES * 128 / 8)        // 1,600,000 x-convert threads
#define CVT_TOTAL (NX8 + 196608)       // 1,796,608 = 256 * 7018
#define HIST_THREADS (2048 * 256)      // grid-stride width of hist section
__global__ __launch_bounds__(256) void cvt_fused_kernel(
    const float* __restrict__ X, ushort_t* __restrict__ Xb,
    const float* __restrict__ W1a, const float* __restrict__ W2a,
    const float* __restrict__ W1b, const float* __restrict__ W2b,
    ushort_t* __restrict__ wt1a, ushort_t* __restrict__ wt2a,
    ushort_t* __restrict__ wt1b, ushort_t* __restrict__ wt2b,
    const int* __restrict__ src, const int* __restrict__ dst,
    int* __restrict__ deg, int nE) {
    int i = blockIdx.x * 256 + threadIdx.x;
    if (i < NX8) {
        const float4 a = ((const float4*)X)[2 * i];
        const float4 b = ((const float4*)X)[2 * i + 1];
        uint4 r;
        r.x = pack2bf(a.x, a.y);
        r.y = pack2bf(a.z, a.w);
        r.z = pack2bf(b.x, b.y);
        r.w = pack2bf(b.z, b.w);
        ((uint4*)Xb)[i] = r;
        return;
    }
    if (i < CVT_TOTAL) {
        i -= NX8;
        if (i < 32768) {                       // W1a [128][256]
            int k = i >> 8, n = i & 255;
            wt1a[n * 128 + k] = f2bf(W1a[i]);
        } else if (i < 98304) {                // W2a [256][256]
            int j = i - 32768, k = j >> 8, n = j & 255;
            wt2a[n * 256 + k] = f2bf(W2a[j]);
        } else if (i < 163840) {               // W1b [256][256]
            int j = i - 98304, k = j >> 8, n = j & 255;
            wt1b[n * 256 + k] = f2bf(W1b[j]);
        } else {                               // W2b [256][128]
            int j = i - 163840, k = j >> 7, n = j & 127;
            wt2b[n * 256 + k] = f2bf(W2b[j]);
        }
        return;
    }
    // hist section: deg count (deg memset'd before this kernel)
    for (int e = i - CVT_TOTAL; e < nE; e += HIST_THREADS) {
        int d = dst[e];
        int s = src[e];
        if ((unsigned)d < (unsigned)N_NODES && (unsigned)s < (unsigned)N_NODES)
            atomicAdd(&deg[d], 1);
    }
}

// ---- fill: R10-exact bucketed (residency-order serialized write window) ----
__global__ __launch_bounds__(256) void fill_kernel(const int* __restrict__ src,
                                                   const int* __restrict__ dst,
                                                   int* __restrict__ cursor,
                                                   int* __restrict__ csr_src, int nE) {
    const int bucket = blockIdx.y;
    for (int e = blockIdx.x * 256 + threadIdx.x; e < nE; e += gridDim.x * 256) {
        int d = dst[e];
        int s = src[e];
        if ((unsigned)d < (unsigned)N_NODES && (unsigned)s < (unsigned)N_NODES &&
            (d >> 13) == bucket) {
            int pos = atomicAdd(&cursor[d], 1);
            csr_src[pos] = s;
        }
    }
}

// ---- scan: deg -> row_ptr (exclusive), cursor copy ----
__global__ __launch_bounds__(256) void scan1_kernel(const int* __restrict__ deg,
                                                    int* __restrict__ bsum, int n) {
    __shared__ int l[256];
    int b = blockIdx.x, t = threadIdx.x;
    int base = b * 1024 + t * 4;
    int s = 0;
#pragma unroll
    for (int k = 0; k < 4; ++k) {
        int i = base + k;
        if (i < n) s += deg[i];
    }
    l[t] = s;
    __syncthreads();
    for (int off = 128; off > 0; off >>= 1) {
        if (t < off) l[t] += l[t + off];
        __syncthreads();
    }
    if (t == 0) bsum[b] = l[0];
}

// scan3 with scan2 folded in: block b computes its own offset from bsum[0..b)
__global__ __launch_bounds__(256) void scan3_kernel(const int* __restrict__ deg,
                                                    const int* __restrict__ bsum,
                                                    int* __restrict__ row_ptr,
                                                    int* __restrict__ cursor,
                                                    int n, int nb) {
    __shared__ int l[256];
    __shared__ int boffs;
    int b = blockIdx.x, t = threadIdx.x;
    // block offset = sum of bsum[0..b)
    l[t] = (t < b && t < nb) ? bsum[t] : 0;
    __syncthreads();
    for (int off = 128; off > 0; off >>= 1) {
        if (t < off) l[t] += l[t + off];
        __syncthreads();
    }
    if (t == 0) boffs = l[0];
    __syncthreads();
    // per-block node prefix
    int base = b * 1024 + t * 4;
    int d[4];
    int s = 0;
#pragma unroll
    for (int k = 0; k < 4; ++k) {
        int i = base + k;
        d[k] = (i < n) ? deg[i] : 0;
        s += d[k];
    }
    l[t] = s;
    __syncthreads();
    for (int off = 1; off < 256; off <<= 1) {
        int add = (t >= off) ? l[t - off] : 0;
        __syncthreads();
        l[t] += add;
        __syncthreads();
    }
    int run = boffs + l[t] - s;
#pragma unroll
    for (int k = 0; k < 4; ++k) {
        int i = base + k;
        if (i < n) {
            row_ptr[i] = run;
            cursor[i] = run;
        }
        run += d[k];
    }
}

// ---- per-node gather (R10-exact): T[i] = X[i] + sum_{j in N(i)} X[j] ----
// Lane loads 16B. G=C/8 lanes per neighbor row, NPW=64/G neighbors per step.
// Fully-predicated batches of U*NPW=16 neighbors: invalid slots load zrow
// (zeroed 512B ws row) -> no serial remainder, U loads in flight per lane.
template <int C, int U>
__global__ __launch_bounds__(256) void agg_gather_kernel(
    const ushort_t* __restrict__ X, ushort_t* __restrict__ T,
    const int* __restrict__ row_ptr, const int* __restrict__ deg,
    const int* __restrict__ csr_src, const ushort_t* __restrict__ zrow, int nN) {
    constexpr int G = C / 8;      // lanes per neighbor row (16 or 32)
    constexpr int NPW = 64 / G;   // neighbors per wave-step (4 or 2)
    constexpr int B = U * NPW;    // neighbors per batch (16)
    const int lane = threadIdx.x & 63;
    const int wid = threadIdx.x >> 6;
    const int node = blockIdx.x * 4 + wid;
    if (node >= nN) return;
    const int sub = lane / G;
    const int coff = (lane % G) * 8;  // ushort offset into row

    float acc[8];
#pragma unroll
    for (int k = 0; k < 8; ++k) acc[k] = 0.f;

    const int base = row_ptr[node];
    const int dg = deg[node];
    for (int j0 = 0; j0 < dg; j0 += 64) {
        int cnt = dg - j0;
        if (cnt > 64) cnt = 64;
        int nidx = (lane < cnt) ? csr_src[base + j0 + lane] : 0;
        if ((unsigned)nidx >= (unsigned)N_NODES) nidx = 0;  // safety clamp
        for (int j = 0; j < cnt; j += B) {
            uint4 v[U];
#pragma unroll
            for (int u = 0; u < U; ++u) {
                int jj = j + u * NPW + sub;
                bool ok = jj < cnt;
                int idx = __shfl(nidx, ok ? jj : 0);
                const ushort_t* p = ok ? (X + (size_t)idx * C) : zrow;
                v[u] = *(const uint4*)(p + coff);
            }
#pragma unroll
            for (int u = 0; u < U; ++u) addu4(acc, v[u]);
        }
    }
    // self term (sub-group 0 only; others would double-count after reduction)
    if (sub == 0) {
        uint4 v = *(const uint4*)(X + (size_t)node * C + coff);
        addu4(acc, v);
    }
    // reduce partials across sub-groups
#pragma unroll
    for (int off = G; off < 64; off <<= 1)
#pragma unroll
        for (int k = 0; k < 8; ++k) acc[k] += __shfl_xor(acc[k], off);

    if (lane < G) {
        uint4 r;
        r.x = pack2bf(acc[0], acc[1]);
        r.y = pack2bf(acc[2], acc[3]);
        r.z = pack2bf(acc[4], acc[5]);
        r.w = pack2bf(acc[6], acc[7]);
        *(uint4*)(T + (size_t)node * C + coff) = r;
    }
}

// ---- fused MLP (R10-exact): C = act2( relu(A@W1+b1) @ W2 + b2 ) ----
// A [M][K1] bf16, Wt1 [256][K1] bf16 (W1 transposed), Wt2 [N2][256] bf16.
// BM=64 rows/block, 256 threads (4 waves), 3 blocks/CU (52KB LDS).
// Stage 1 role-swapped (av = Wt1 rows, bv = A rows) -> lane holds 4
// hidden-contiguous f32 -> packed uint2 LDS write of u1 [node][256],
// XOR-swizzle ((node&7)<<4). Stage 2: av = U node rows, bv = Wt2 rows.
template <int K1, int N2, bool RELU2, typename OT>
__global__ __launch_bounds__(256, 3) void mlp_kernel(
    const ushort_t* __restrict__ A, const ushort_t* __restrict__ Wt1,
    const float* __restrict__ b1, const ushort_t* __restrict__ Wt2,
    const float* __restrict__ b2, OT* __restrict__ C, int M) {
    constexpr int N1 = 256, BM = 64, BK = 32;
    constexpr int NPW2 = N2 / 4;    // out-cols per wave in stage 2 (64 or 32)
    constexpr int RN2 = NPW2 / 16;  // frags / staging issues per wave (4 or 2)
    __shared__ ushort_t As[BM * BK];  // input tile  [64][32]
    __shared__ ushort_t Bs[N1 * BK];  // weight tile [256][32] (both stages)
    __shared__ ushort_t U[BM * N1];   // u1 tile [64][256], XOR-swizzled

    const int lane = threadIdx.x & 63;
    const int wid = threadIdx.x >> 6;
    const int l15 = lane & 15;
    const int q = lane >> 4;
    const int srow = lane >> 2;       // 0..15: row within 16-row DMA group
    const int scol = (lane & 3) * 8;  // ushort offset within 64B row
    const int bm = blockIdx.x * BM;

    floatx4 acc[4][4];
#pragma unroll
    for (int mi = 0; mi < 4; ++mi)
#pragma unroll
        for (int ni = 0; ni < 4; ++ni) {
            floatx4 z = {0.f, 0.f, 0.f, 0.f};
            acc[mi][ni] = z;
        }

    // ---- stage 1: u1^T = Wt1 * A^T over K1 ----
    for (int kt = 0; kt < K1; kt += BK) {
        {   // As: wave wid stages rows [wid*16, wid*16+16)
            const int gr = bm + wid * 16 + srow;
            if (gr < M)
                GLOAD_LDS16(A + (size_t)gr * K1 + kt + scol, &As[(wid * 16) * BK]);
        }
#pragma unroll
        for (int u = 0; u < 4; ++u) {  // Bs: wave wid stages rows [wid*64, +64)
            const int row = wid * 64 + u * 16;
            GLOAD_LDS16(Wt1 + (size_t)(row + srow) * K1 + kt + scol, &Bs[row * BK]);
        }
        __syncthreads();  // drains vmcnt(0): DMA complete
        bf16x8 av[4], bv[4];
#pragma unroll
        for (int mi = 0; mi < 4; ++mi)
            av[mi] = *(const bf16x8*)&Bs[(wid * 64 + mi * 16 + l15) * BK + q * 8];
#pragma unroll
        for (int ni = 0; ni < 4; ++ni)
            bv[ni] = *(const bf16x8*)&As[(ni * 16 + l15) * BK + q * 8];
#pragma unroll
        for (int mi = 0; mi < 4; ++mi)
#pragma unroll
            for (int ni = 0; ni < 4; ++ni)
                acc[mi][ni] = __builtin_amdgcn_mfma_f32_16x16x32_bf16(
                    av[mi], bv[ni], acc[mi][ni], 0, 0, 0);
        __syncthreads();
    }

    // ---- bias1 + relu + pack -> U[node][hidden] (swizzled) ----
#pragma unroll
    for (int mi = 0; mi < 4; ++mi) {
        const int h0 = wid * 64 + mi * 16 + q * 4;
        const float4 b4 = *(const float4*)&b1[h0];
#pragma unroll
        for (int ni = 0; ni < 4; ++ni) {
            const int node = ni * 16 + l15;
            float v0 = acc[mi][ni][0] + b4.x; v0 = v0 > 0.f ? v0 : 0.f;
            float v1 = acc[mi][ni][1] + b4.y; v1 = v1 > 0.f ? v1 : 0.f;
            float v2 = acc[mi][ni][2] + b4.z; v2 = v2 > 0.f ? v2 : 0.f;
            float v3 = acc[mi][ni][3] + b4.w; v3 = v3 > 0.f ? v3 : 0.f;
            uint2 w;
            w.x = pack2bf(v0, v1);
            w.y = pack2bf(v2, v3);
            int byte = node * (N1 * 2) + h0 * 2;
            byte ^= (node & 7) << 4;
            *(uint2*)((char*)U + byte) = w;
        }
    }
    __syncthreads();

    // ---- stage 2: C = u1 @ W2 over N1 ----
#pragma unroll
    for (int mi = 0; mi < 4; ++mi)
#pragma unroll
        for (int ni = 0; ni < 4; ++ni) {
            floatx4 z = {0.f, 0.f, 0.f, 0.f};
            acc[mi][ni] = z;
        }

    for (int kt = 0; kt < N1; kt += BK) {
#pragma unroll
        for (int u = 0; u < RN2; ++u) {  // Bs <- Wt2 rows [wid*NPW2, +NPW2)
            const int row = wid * NPW2 + u * 16;
            GLOAD_LDS16(Wt2 + (size_t)(row + srow) * N1 + kt + scol, &Bs[row * BK]);
        }
        __syncthreads();
        bf16x8 av[4], bv[RN2];
#pragma unroll
        for (int mi = 0; mi < 4; ++mi) {
            const int node = mi * 16 + l15;
            const int byte =
                (node * (N1 * 2) + kt * 2 + q * 16) ^ ((node & 7) << 4);
            av[mi] = *(const bf16x8*)((const char*)U + byte);
        }
#pragma unroll
        for (int ni = 0; ni < RN2; ++ni)
            bv[ni] = *(const bf16x8*)&Bs[(wid * NPW2 + ni * 16 + l15) * BK + q * 8];
#pragma unroll
        for (int mi = 0; mi < 4; ++mi)
#pragma unroll
            for (int ni = 0; ni < RN2; ++ni)
                acc[mi][ni] = __builtin_amdgcn_mfma_f32_16x16x32_bf16(
                    av[mi], bv[ni], acc[mi][ni], 0, 0, 0);
        __syncthreads();
    }

    // ---- epilogue: bias2 (+relu), store ----
    float bval[RN2];
#pragma unroll
    for (int ni = 0; ni < RN2; ++ni) bval[ni] = b2[wid * NPW2 + ni * 16 + l15];
#pragma unroll
    for (int mi = 0; mi < 4; ++mi) {
#pragma unroll
        for (int r = 0; r < 4; ++r) {
            const int row = bm + mi * 16 + q * 4 + r;
            if (row < M) {
#pragma unroll
                for (int ni = 0; ni < RN2; ++ni) {
                    const int col = wid * NPW2 + ni * 16 + l15;
                    float v = acc[mi][ni][r] + bval[ni];
                    if (RELU2) v = v > 0.f ? v : 0.f;
                    if constexpr (sizeof(OT) == 2)
                        C[(size_t)row * N2 + col] = f2bf(v);
                    else
                        C[(size_t)row * N2 + col] = v;
                }
            }
        }
    }
}

extern "C" void kernel_launch(void* const* d_in, const int* in_sizes, int n_in,
                              void* d_out, int out_size, void* d_ws, size_t ws_size,
                              hipStream_t stream) {
    const float* x   = (const float*)d_in[0];
    const int*   ei  = (const int*)d_in[1];
    const float* W1a = (const float*)d_in[2];
    const float* b1a = (const float*)d_in[3];
    const float* W2a = (const float*)d_in[4];
    const float* b2a = (const float*)d_in[5];
    const float* W1b = (const float*)d_in[6];
    const float* b1b = (const float*)d_in[7];
    const float* W2b = (const float*)d_in[8];
    const float* b2b = (const float*)d_in[9];
    const int* src = ei;
    const int* dst = ei + N_EDGES;
    float* out = (float*)d_out;

    // ---- workspace layout (~85MB; 103MB proven to fit) ----
    char* base = (char*)d_ws;
    size_t o = 0;
    ushort_t* wt1a = (ushort_t*)(base + o); o += 128 * 256 * 2;
    ushort_t* wt2a = (ushort_t*)(base + o); o += 256 * 256 * 2;
    ushort_t* wt1b = (ushort_t*)(base + o); o += 256 * 256 * 2;
    ushort_t* wt2b = (ushort_t*)(base + o); o += 256 * 128 * 2;
    o = (o + 255) & ~(size_t)255;
    ushort_t* zrow = (ushort_t*)(base + o); o += 512;          // memset'd
    int* deg     = (int*)(base + o); o += (size_t)N_NODES * 4; // memset'd
    int* row_ptr = (int*)(base + o); o += (size_t)N_NODES * 4;
    int* cursor  = (int*)(base + o); o += (size_t)N_NODES * 4;
    int* bsum    = (int*)(base + o); o += 128 * 4;
    o = (o + 255) & ~(size_t)255;
    int* csr_src = (int*)(base + o); o += (size_t)N_EDGES * 4;
    o = (o + 255) & ~(size_t)255;
    ushort_t* t1   = (ushort_t*)(base + o); o += (size_t)N_NODES * 128 * 2;
    ushort_t* tbig = (ushort_t*)(base + o); o += (size_t)N_NODES * 256 * 2;  // t2
    o += 128 * 1024;  // guard
    (void)ws_size; (void)o; (void)in_sizes; (void)n_in; (void)out_size;

    ushort_t* inter = (ushort_t*)d_out;  // xb, then h (d_out = 51.2MB)
    ushort_t* xb    = (ushort_t*)d_out;  // bf16 x, dead after agg1 (mlp_a overwrites)

    // ---- memset FIRST (deg must be zero before fused hist) ----
    hipMemsetAsync(zrow, 0, 512 + (size_t)N_NODES * 4, stream);  // zrow + deg

    // ---- conversions + hist in one launch ----
    cvt_fused_kernel<<<CVT_TOTAL / 256 + 2048, 256, 0, stream>>>(
        x, xb, W1a, W2a, W1b, W2b, wt1a, wt2a, wt1b, wt2b, src, dst, deg, N_EDGES);

    // ---- CSR: scan1 -> merged scan3 -> bucketed fill (R10) ----
    const int NB = (N_NODES + 1023) / 1024;  // 98
    scan1_kernel<<<NB, 256, 0, stream>>>(deg, bsum, N_NODES);
    scan3_kernel<<<NB, 256, 0, stream>>>(deg, bsum, row_ptr, cursor, N_NODES, NB);
    fill_kernel<<<dim3(1024, NBUCK), 256, 0, stream>>>(src, dst, cursor, csr_src,
                                                       N_EDGES);

    const int ga = (N_NODES + 3) / 4;        // 25000
    const int gf = (N_NODES + 63) / 64;      // 1563 fused-MLP blocks

    // ---- layer 1 ----
    // t1 = xb + segsum(xb)        (d_out -> ws)
    agg_gather_kernel<128, 4><<<ga, 256, 0, stream>>>(xb, t1, row_ptr, deg,
                                                      csr_src, zrow, N_NODES);
    // h = relu( relu(t1@W1a+b1a) @ W2a + b2a )   (ws -> d_out, overwrites dead xb)
    mlp_kernel<128, 256, true, ushort_t><<<gf, 256, 0, stream>>>(
        t1, wt1a, b1a, wt2a, b2a, inter, N_NODES);

    // ---- layer 2 ----
    // t2 = h + segsum(h)          (d_out -> ws)
    agg_gather_kernel<256, 8><<<ga, 256, 0, stream>>>(inter, tbig, row_ptr,
                                                      deg, csr_src, zrow, N_NODES);
    // out = relu(t2@W1b+b1b) @ W2b + b2b         (ws -> d_out, overwrites dead h)
    mlp_kernel<256, 128, false, float><<<gf, 256, 0, stream>>>(
        tbig, wt1b, b1b, wt2b, b2b, out, N_NODES);
}